// Round 3
// baseline (408.604 us; speedup 1.0000x reference)
//
#include <hip/hip_runtime.h>
#include <hip/hip_fp16.h>

// ForwardDeformer (B=4, N=250000, J=55, vol [55,16,64,64]).
// R1: pre-blend voxel weights with matrices (linearity) -> per-voxel 4x4 mats.
// R2 was latency-bound (VALU 18%, HBM 21%): 32 cache lines gathered per point,
// ~2-3 loads in flight (VGPR=44), and ~every wave ran both mask paths serially.
// R3: (1) merged fp16 table -> ONE 64B line per corner (8 lines/point);
//     (2) depth-2 corner pipeline for load ILP; (3) LDS mask-compaction so
//     masked (VALU-heavy) and unmasked (gather-heavy) lanes run as separate
//     full waves concurrently within each block.

#define JNT 55
#define VD  16
#define VH  64
#define VW  64
#define NVOX (VD * VH * VW)   // 65536

// ---------------------------------------------------------------------------
// Pre-pass: tab[(b*NVOX+v)*32] = { half Mi[16], half Mv_b[16] }  (64 B entry)
//   Mi  = sum_j vol[j,v] * tfs_inv[j]
//   Mv  = sum_j vol[j,v] * tfs[b,j]
// ---------------------------------------------------------------------------
__global__ __launch_bounds__(256, 2) void build_tab_k(
    const float* __restrict__ vol, const float* __restrict__ tfs,
    const float* __restrict__ tfs_inv, __half* __restrict__ tab, int B)
{
    int v = blockIdx.x * 256 + threadIdx.x;
    if (v >= NVOX) return;
    float w[JNT];
#pragma unroll
    for (int j = 0; j < JNT; ++j) w[j] = vol[j * NVOX + v];

    float Mi[16];
#pragma unroll
    for (int i = 0; i < 16; ++i) Mi[i] = 0.f;
#pragma unroll
    for (int j = 0; j < JNT; ++j) {
        float wj = w[j];
#pragma unroll
        for (int i = 0; i < 16; ++i) Mi[i] = fmaf(wj, tfs_inv[j * 16 + i], Mi[i]);
    }
    float hi[8];
#pragma unroll
    for (int i = 0; i < 8; ++i)
        hi[i] = __builtin_bit_cast(float, __floats2half2_rn(Mi[2*i], Mi[2*i+1]));

    for (int b = 0; b < B; ++b) {
        const float* tb = tfs + (size_t)b * JNT * 16;
        float Mv[16];
#pragma unroll
        for (int i = 0; i < 16; ++i) Mv[i] = 0.f;
#pragma unroll
        for (int j = 0; j < JNT; ++j) {
            float wj = w[j];
#pragma unroll
            for (int i = 0; i < 16; ++i) Mv[i] = fmaf(wj, tb[j * 16 + i], Mv[i]);
        }
        float hv[8];
#pragma unroll
        for (int i = 0; i < 8; ++i)
            hv[i] = __builtin_bit_cast(float, __floats2half2_rn(Mv[2*i], Mv[2*i+1]));

        float4* d4 = (float4*)(tab + ((size_t)b * NVOX + v) * 32);
        d4[0] = make_float4(hi[0], hi[1], hi[2], hi[3]);
        d4[1] = make_float4(hi[4], hi[5], hi[6], hi[7]);
        d4[2] = make_float4(hv[0], hv[1], hv[2], hv[3]);
        d4[3] = make_float4(hv[4], hv[5], hv[6], hv[7]);
    }
}

// Accumulate 8 fp16 values (one float4 of packed half2) into a[0..7] with weight cw.
__device__ __forceinline__ void acc8(float cw, float4 r, float* a)
{
    float rr[4] = {r.x, r.y, r.z, r.w};
#pragma unroll
    for (int k = 0; k < 4; ++k) {
        __half2 h = __builtin_bit_cast(__half2, rr[k]);
        float2 f = __half22float2(h);
        a[2*k]     = fmaf(cw, f.x, a[2*k]);
        a[2*k + 1] = fmaf(cw, f.y, a[2*k + 1]);
    }
}

__device__ __forceinline__ void epilogue(
    int b, int n, int N, float x, float y, float z,
    const float* A, const float* Ai,
    const float* __restrict__ shoff, const float* __restrict__ pooff,
    const float* __restrict__ poori,
    float* __restrict__ out_xd, float* __restrict__ out_w)
{
    size_t pid = (size_t)b * N + n;
    size_t p3  = pid * 3;
    size_t n3  = (size_t)n * 3;
    float c0 = Ai[0]*x + Ai[1]*y + Ai[2]*z  + Ai[3];
    float c1 = Ai[4]*x + Ai[5]*y + Ai[6]*z  + Ai[7];
    float c2 = Ai[8]*x + Ai[9]*y + Ai[10]*z + Ai[11];
    float sx = c0 - poori[n3 + 0] + shoff[p3 + 0] + pooff[p3 + 0];
    float sy = c1 - poori[n3 + 1] + shoff[p3 + 1] + pooff[p3 + 1];
    float sz = c2 - poori[n3 + 2] + shoff[p3 + 2] + pooff[p3 + 2];
    out_xd[p3 + 0] = A[0]*sx + A[1]*sy + A[2]*sz  + A[3];
    out_xd[p3 + 1] = A[4]*sx + A[5]*sy + A[6]*sz  + A[7];
    out_xd[p3 + 2] = A[8]*sx + A[9]*sy + A[10]*sz + A[11];

    float4* ow = (float4*)(out_w + pid * 16);
#pragma unroll
    for (int i = 0; i < 4; ++i) {
        float a0 = A[i*4+0], a1 = A[i*4+1], a2 = A[i*4+2], a3 = A[i*4+3];
        float4 r;
        r.x = a0*Ai[0] + a1*Ai[4] + a2*Ai[8]  + a3*Ai[12];
        r.y = a0*Ai[1] + a1*Ai[5] + a2*Ai[9]  + a3*Ai[13];
        r.z = a0*Ai[2] + a1*Ai[6] + a2*Ai[10] + a3*Ai[14];
        r.w = a0*Ai[3] + a1*Ai[7] + a2*Ai[11] + a3*Ai[15];
        ow[i] = r;
    }
}

// ---------------------------------------------------------------------------
// Main kernel. Per block: LDS-compact masked/unmasked point lists, then
// phase A (masked, lbsw blend) on threads [0,mcnt) and phase B (unmasked,
// table gather) on threads counted from the TOP (255-tx) so the two
// populations execute on different waves concurrently.
// ---------------------------------------------------------------------------
template <bool USE_TAB>
__global__ __launch_bounds__(256, 3) void deform_k(
    const float* __restrict__ xc,
    const float* __restrict__ shoff,
    const float* __restrict__ pooff,
    const float* __restrict__ tfs,        // [B, J, 16]
    const float* __restrict__ tfs_inv,    // [J, 16]
    const float* __restrict__ poori,      // [N, 3]
    const float* __restrict__ lbsw,       // [N, J]
    const int*   __restrict__ mask,       // [N]
    const __half* __restrict__ tab,       // [B, NVOX, 32]
    const float* __restrict__ vol,        // [J, NVOX] (fallback)
    const float* __restrict__ offk,
    const float* __restrict__ sck,
    float* __restrict__ out_xd,
    float* __restrict__ out_w,
    int N)
{
    int b    = blockIdx.y;
    int base = blockIdx.x * 256;
    int tx   = threadIdx.x;
    int nc   = base + tx;
    bool valid = nc < N;
    bool m = valid && (mask[nc] != 0);

    __shared__ unsigned short ml[256], ul[256];
    __shared__ int sc[10];   // [0..3] masked wave offsets, [4..7] unmasked, [8]=mcnt, [9]=ucnt

    int lane = tx & 63, wid = tx >> 6;
    unsigned long long bm = __ballot(m);
    unsigned long long bu = __ballot(valid && !m);
    if (lane == 0) { sc[wid] = (int)__popcll(bm); sc[4 + wid] = (int)__popcll(bu); }
    __syncthreads();
    if (tx == 0) {
        int s = 0;
        for (int i = 0; i < 4; ++i) { int t = sc[i]; sc[i] = s; s += t; }
        sc[8] = s; s = 0;
        for (int i = 0; i < 4; ++i) { int t = sc[4 + i]; sc[4 + i] = s; s += t; }
        sc[9] = s;
    }
    __syncthreads();
    unsigned long long below = ((unsigned long long)1 << lane) - 1;
    if (m)          ml[sc[wid]     + (int)__popcll(bm & below)] = (unsigned short)tx;
    else if (valid) ul[sc[4 + wid] + (int)__popcll(bu & below)] = (unsigned short)tx;
    __syncthreads();
    int mcnt = sc[8], ucnt = sc[9];

    // ---------------- Phase A: masked (pure VALU blend from lbsw) ----------
    if (tx < mcnt) {
        int n = base + ml[tx];
        size_t p3 = ((size_t)b * N + n) * 3;
        float x = xc[p3], y = xc[p3 + 1], z = xc[p3 + 2];
        float A[16], Ai[16];
#pragma unroll
        for (int i = 0; i < 16; ++i) { A[i] = 0.f; Ai[i] = 0.f; }
        const float*  lp  = lbsw + (size_t)n * JNT;
        const float4* ti4 = (const float4*)tfs_inv;
        const float4* tb4 = (const float4*)(tfs + (size_t)b * JNT * 16);
        for (int j = 0; j < JNT; ++j) {
            float wj = lp[j];
#pragma unroll
            for (int q = 0; q < 4; ++q) {
                float4 r = ti4[j * 4 + q];
                Ai[4*q+0] = fmaf(wj, r.x, Ai[4*q+0]);
                Ai[4*q+1] = fmaf(wj, r.y, Ai[4*q+1]);
                Ai[4*q+2] = fmaf(wj, r.z, Ai[4*q+2]);
                Ai[4*q+3] = fmaf(wj, r.w, Ai[4*q+3]);
            }
#pragma unroll
            for (int q = 0; q < 4; ++q) {
                float4 r = tb4[j * 4 + q];
                A[4*q+0] = fmaf(wj, r.x, A[4*q+0]);
                A[4*q+1] = fmaf(wj, r.y, A[4*q+1]);
                A[4*q+2] = fmaf(wj, r.z, A[4*q+2]);
                A[4*q+3] = fmaf(wj, r.w, A[4*q+3]);
            }
        }
        epilogue(b, n, N, x, y, z, A, Ai, shoff, pooff, poori, out_xd, out_w);
    }

    // ---------------- Phase B: unmasked (table gather), top-down -----------
    int ub = 255 - tx;
    if (ub < ucnt) {
        int n = base + ul[ub];
        size_t p3 = ((size_t)b * N + n) * 3;
        float x = xc[p3], y = xc[p3 + 1], z = xc[p3 + 2];

        float px = (x + offk[0]) * sck[0];
        float py = (y + offk[1]) * sck[1];
        float pz = (z + offk[2]) * sck[2];
        float ix = fminf(fmaxf((px + 1.f) * 0.5f * (VW - 1), 0.f), (float)(VW - 1));
        float iy = fminf(fmaxf((py + 1.f) * 0.5f * (VH - 1), 0.f), (float)(VH - 1));
        float iz = fminf(fmaxf((pz + 1.f) * 0.5f * (VD - 1), 0.f), (float)(VD - 1));
        float fx = floorf(ix), fy = floorf(iy), fz = floorf(iz);
        float wx = ix - fx,    wy = iy - fy,    wz = iz - fz;
        int x0 = (int)fx, y0 = (int)fy, z0 = (int)fz;
        int x1 = min(x0 + 1, VW - 1);
        int y1 = min(y0 + 1, VH - 1);
        int z1 = min(z0 + 1, VD - 1);

        float A[16], Ai[16];
#pragma unroll
        for (int i = 0; i < 16; ++i) { A[i] = 0.f; Ai[i] = 0.f; }

        if (USE_TAB) {
            float cwx[2] = {1.f - wx, wx};
            float cwy[2] = {1.f - wy, wy};
            float cwz[2] = {1.f - wz, wz};
            int   xs[2] = {x0, x1}, ys[2] = {y0, y1}, zs[2] = {z0, z1};
            int   vox[8]; float cw[8];
#pragma unroll
            for (int c = 0; c < 8; ++c) {
                int cz = c >> 2, cy = (c >> 1) & 1, cx = c & 1;
                vox[c] = (zs[cz] * VH + ys[cy]) * VW + xs[cx];
                cw[c]  = cwz[cz] * cwy[cy] * cwx[cx];
            }
            const __half* tbb = tab + (size_t)b * NVOX * 32;
            // depth-2 pipelined corner loop: one 64B line per corner
            float4 s0[4], s1[4];
            {
                const float4* p0 = (const float4*)(tbb + (size_t)vox[0] * 32);
                const float4* p1 = (const float4*)(tbb + (size_t)vox[1] * 32);
                s0[0]=p0[0]; s0[1]=p0[1]; s0[2]=p0[2]; s0[3]=p0[3];
                s1[0]=p1[0]; s1[1]=p1[1]; s1[2]=p1[2]; s1[3]=p1[3];
            }
#pragma unroll
            for (int c = 0; c < 8; ++c) {
                float4* cur = (c & 1) ? s1 : s0;
                float cwc = cw[c];
                acc8(cwc, cur[0], Ai);
                acc8(cwc, cur[1], Ai + 8);
                acc8(cwc, cur[2], A);
                acc8(cwc, cur[3], A + 8);
                if (c + 2 < 8) {
                    const float4* pn = (const float4*)(tbb + (size_t)vox[c + 2] * 32);
                    cur[0]=pn[0]; cur[1]=pn[1]; cur[2]=pn[2]; cur[3]=pn[3];
                }
            }
        } else {
            // fallback: per-channel 8-corner gather from native vol, fused blend
            float w00 = (1.f - wz) * (1.f - wy), w01 = (1.f - wz) * wy;
            float w10 = wz * (1.f - wy),         w11 = wz * wy;
            int o00 = (z0 * VH + y0) * VW, o01 = (z0 * VH + y1) * VW;
            int o10 = (z1 * VH + y0) * VW, o11 = (z1 * VH + y1) * VW;
            const float* tb = tfs + (size_t)b * JNT * 16;
#pragma unroll 4
            for (int j = 0; j < JNT; ++j) {
                const float* vp = vol + (size_t)j * NVOX;
                float v000 = vp[o00 + x0], v001 = vp[o00 + x1];
                float v010 = vp[o01 + x0], v011 = vp[o01 + x1];
                float v100 = vp[o10 + x0], v101 = vp[o10 + x1];
                float v110 = vp[o11 + x0], v111 = vp[o11 + x1];
                float c0 = w00 * v000 + w01 * v010 + w10 * v100 + w11 * v110;
                float c1 = w00 * v001 + w01 * v011 + w10 * v101 + w11 * v111;
                float wj = c0 + wx * (c1 - c0);
#pragma unroll
                for (int i = 0; i < 16; ++i) Ai[i] = fmaf(wj, tfs_inv[j*16+i], Ai[i]);
#pragma unroll
                for (int i = 0; i < 16; ++i) A[i]  = fmaf(wj, tb[j*16+i],      A[i]);
            }
        }
        epilogue(b, n, N, x, y, z, A, Ai, shoff, pooff, poori, out_xd, out_w);
    }
}

extern "C" void kernel_launch(void* const* d_in, const int* in_sizes, int n_in,
                              void* d_out, int out_size, void* d_ws, size_t ws_size,
                              hipStream_t stream)
{
    const float* xc    = (const float*)d_in[0];
    const float* shoff = (const float*)d_in[1];
    const float* pooff = (const float*)d_in[2];
    const float* tfs   = (const float*)d_in[3];
    const float* tfsi  = (const float*)d_in[4];
    const float* poori = (const float*)d_in[5];
    const float* lbsw  = (const float*)d_in[6];
    const int*   mask  = (const int*)d_in[7];
    const float* vol   = (const float*)d_in[8];
    const float* offk  = (const float*)d_in[9];
    const float* sck   = (const float*)d_in[10];

    int N = in_sizes[5] / 3;          // poseoff_ori [1,N,3]
    int B = in_sizes[0] / (3 * N);    // xc [B,N,3]
    float* out_xd = (float*)d_out;
    float* out_w  = (float*)d_out + (size_t)B * N * 3;

    size_t tbytes = (size_t)B * NVOX * 32 * sizeof(__half);  // 16.78 MB @ B=4
    __half* tab = (__half*)d_ws;
    bool use_tab = (ws_size >= tbytes);

    dim3 blk(256);
    dim3 grd((N + 255) / 256, B);

    if (use_tab) {
        build_tab_k<<<dim3((NVOX + 255) / 256), blk, 0, stream>>>(vol, tfs, tfsi, tab, B);
        deform_k<true><<<grd, blk, 0, stream>>>(
            xc, shoff, pooff, tfs, tfsi, poori, lbsw, mask, tab, vol, offk, sck,
            out_xd, out_w, N);
    } else {
        deform_k<false><<<grd, blk, 0, stream>>>(
            xc, shoff, pooff, tfs, tfsi, poori, lbsw, mask, tab, vol, offk, sck,
            out_xd, out_w, N);
    }
}

// Round 4
// 359.436 us; speedup vs baseline: 1.1368x; 1.1368x over previous
//
#include <hip/hip_runtime.h>
#include <hip/hip_fp16.h>

// ForwardDeformer (B=4, N=250000, J=55, vol [55,16,64,64]).
// R1: pre-blend voxel weights with matrices (linearity) -> per-voxel 4x4 mats.
// R3 post-mortem: kernel is TA-request-bound (divergent gathers: ~60 cache-line
// requests per point). R4: (a) 4-lane team gather of merged 64B fp16 table
// entries -> 1 request per corner (8/pt instead of 64); (b) global mask
// partition -> masked points (VALU-bound, b-folded) and gather points
// (TA-bound) run as separate full waves; (c) masked lbsw rows read 16B-aligned,
// tfs/tfs_inv staged in LDS (padded stride 20 -> conflict-free).

#define JNT 55
#define VD  16
#define VH  64
#define VW  64
#define NVOX (VD * VH * VW)   // 65536

// ---------------------------------------------------------------------------
// Pre-pass 1: tab[(b*NVOX+v)] = 64B line { half Mi[16], half Mv_b[16] }.
// ---------------------------------------------------------------------------
__global__ __launch_bounds__(256, 2) void build_tab_k(
    const float* __restrict__ vol, const float* __restrict__ tfs,
    const float* __restrict__ tfs_inv, __half* __restrict__ tab, int B)
{
    int v = blockIdx.x * 256 + threadIdx.x;
    if (v >= NVOX) return;
    float w[JNT];
#pragma unroll
    for (int j = 0; j < JNT; ++j) w[j] = vol[j * NVOX + v];

    float Mi[16];
#pragma unroll
    for (int i = 0; i < 16; ++i) Mi[i] = 0.f;
#pragma unroll
    for (int j = 0; j < JNT; ++j) {
        float wj = w[j];
#pragma unroll
        for (int i = 0; i < 16; ++i) Mi[i] = fmaf(wj, tfs_inv[j * 16 + i], Mi[i]);
    }
    float hi[8];
#pragma unroll
    for (int i = 0; i < 8; ++i)
        hi[i] = __builtin_bit_cast(float, __floats2half2_rn(Mi[2*i], Mi[2*i+1]));

    for (int b = 0; b < B; ++b) {
        const float* tb = tfs + (size_t)b * JNT * 16;
        float Mv[16];
#pragma unroll
        for (int i = 0; i < 16; ++i) Mv[i] = 0.f;
#pragma unroll
        for (int j = 0; j < JNT; ++j) {
            float wj = w[j];
#pragma unroll
            for (int i = 0; i < 16; ++i) Mv[i] = fmaf(wj, tb[j * 16 + i], Mv[i]);
        }
        float hv[8];
#pragma unroll
        for (int i = 0; i < 8; ++i)
            hv[i] = __builtin_bit_cast(float, __floats2half2_rn(Mv[2*i], Mv[2*i+1]));

        float4* d4 = (float4*)(tab + ((size_t)b * NVOX + v) * 32);
        d4[0] = make_float4(hi[0], hi[1], hi[2], hi[3]);
        d4[1] = make_float4(hi[4], hi[5], hi[6], hi[7]);
        d4[2] = make_float4(hv[0], hv[1], hv[2], hv[3]);
        d4[3] = make_float4(hv[4], hv[5], hv[6], hv[7]);
    }
}

// ---------------------------------------------------------------------------
// Pre-pass 2: partition point indices. Masked indices grow from idx[0],
// unmasked from idx[N-1] downward. ctr[0]=cntM, ctr[1]=cntU.
// ---------------------------------------------------------------------------
__global__ __launch_bounds__(256) void partition_k(
    const int* __restrict__ mask, int* __restrict__ idx, int* __restrict__ ctr, int N)
{
    __shared__ int sm[4], su[4], sb[2];
    int tx = threadIdx.x;
    int n = blockIdx.x * 256 + tx;
    bool valid = n < N;
    bool m = valid && (mask[n] != 0);
    bool u = valid && !m;
    int lane = tx & 63, wid = tx >> 6;
    unsigned long long bm = __ballot(m), bu = __ballot(u);
    if (lane == 0) { sm[wid] = (int)__popcll(bm); su[wid] = (int)__popcll(bu); }
    __syncthreads();
    if (tx == 0) {
        int tm = 0, tu = 0;
        for (int i = 0; i < 4; ++i) {
            int a = sm[i]; sm[i] = tm; tm += a;
            int c = su[i]; su[i] = tu; tu += c;
        }
        sb[0] = atomicAdd(&ctr[0], tm);
        sb[1] = atomicAdd(&ctr[1], tu);
    }
    __syncthreads();
    unsigned long long below = ((unsigned long long)1 << lane) - 1;
    if (m) idx[sb[0] + sm[wid] + (int)__popcll(bm & below)] = n;
    if (u) idx[N - 1 - (sb[1] + su[wid] + (int)__popcll(bu & below))] = n;
}

// Accumulate 8 fp16 values (one float4 of packed half2) into a[0..7] with weight cw.
__device__ __forceinline__ void acc8(float cw, float4 r, float* a)
{
    float rr[4] = {r.x, r.y, r.z, r.w};
#pragma unroll
    for (int kk = 0; kk < 4; ++kk) {
        __half2 h = __builtin_bit_cast(__half2, rr[kk]);
        float2 f = __half22float2(h);
        a[2*kk]     = fmaf(cw, f.x, a[2*kk]);
        a[2*kk + 1] = fmaf(cw, f.y, a[2*kk + 1]);
    }
}

__device__ __forceinline__ void epilogue(
    int b, int n, int N, float x, float y, float z,
    const float* A, const float* Ai,
    const float* __restrict__ shoff, const float* __restrict__ pooff,
    const float* __restrict__ poori,
    float* __restrict__ out_xd, float* __restrict__ out_w)
{
    size_t pid = (size_t)b * N + n;
    size_t p3  = pid * 3;
    size_t n3  = (size_t)n * 3;
    float c0 = Ai[0]*x + Ai[1]*y + Ai[2]*z  + Ai[3];
    float c1 = Ai[4]*x + Ai[5]*y + Ai[6]*z  + Ai[7];
    float c2 = Ai[8]*x + Ai[9]*y + Ai[10]*z + Ai[11];
    float sx = c0 - poori[n3 + 0] + shoff[p3 + 0] + pooff[p3 + 0];
    float sy = c1 - poori[n3 + 1] + shoff[p3 + 1] + pooff[p3 + 1];
    float sz = c2 - poori[n3 + 2] + shoff[p3 + 2] + pooff[p3 + 2];
    out_xd[p3 + 0] = A[0]*sx + A[1]*sy + A[2]*sz  + A[3];
    out_xd[p3 + 1] = A[4]*sx + A[5]*sy + A[6]*sz  + A[7];
    out_xd[p3 + 2] = A[8]*sx + A[9]*sy + A[10]*sz + A[11];

    float4* ow = (float4*)(out_w + pid * 16);
#pragma unroll
    for (int i = 0; i < 4; ++i) {
        float a0 = A[i*4+0], a1 = A[i*4+1], a2 = A[i*4+2], a3 = A[i*4+3];
        float4 r;
        r.x = a0*Ai[0] + a1*Ai[4] + a2*Ai[8]  + a3*Ai[12];
        r.y = a0*Ai[1] + a1*Ai[5] + a2*Ai[9]  + a3*Ai[13];
        r.z = a0*Ai[2] + a1*Ai[6] + a2*Ai[10] + a3*Ai[14];
        r.w = a0*Ai[3] + a1*Ai[7] + a2*Ai[11] + a3*Ai[15];
        ow[i] = r;
    }
}

// ---------------------------------------------------------------------------
// Main kernel (B compile-time). Virtual item space over a grid-stride loop:
//   [0, cntM64)              : masked points, 1 thread each, all B batches
//   [cntM64, cntM64+4*B*cntU): unmasked, 4-lane teams per (b, point)
// ---------------------------------------------------------------------------
template <int B>
__global__ __launch_bounds__(256, 4) void main_k(
    const float* __restrict__ xc,
    const float* __restrict__ shoff,
    const float* __restrict__ pooff,
    const float* __restrict__ tfs,        // [B, J, 16]
    const float* __restrict__ tfs_inv,    // [J, 16]
    const float* __restrict__ poori,      // [N, 3]
    const float* __restrict__ lbsw,       // [N, J]
    const __half* __restrict__ tab,       // [B, NVOX, 32 halves]
    const int*   __restrict__ idx,        // [N] partitioned indices
    const int*   __restrict__ ctr,        // [2] cntM, cntU
    const float* __restrict__ offk,
    const float* __restrict__ sck,
    float* __restrict__ out_xd,
    float* __restrict__ out_w,
    int N)
{
    // LDS-staged matrices, rows padded to 20 floats (conflict-free b128 reads).
    __shared__ float sT[JNT * 20 + JNT * B * 20];
    for (int t = threadIdx.x; t < JNT * 16 + JNT * B * 16; t += 256) {
        if (t < JNT * 16) {
            int j = t >> 4, i = t & 15;
            sT[j * 20 + i] = tfs_inv[t];
        } else {
            int q = t - JNT * 16;
            int j = q / (B * 16), r = q % (B * 16), b = r >> 4, i = r & 15;
            sT[JNT * 20 + (j * B + b) * 20 + i] = tfs[((size_t)b * JNT + j) * 16 + i];
        }
    }
    __syncthreads();

    int cntM = ctr[0], cntU = ctr[1];
    int cntM64 = (cntM + 63) & ~63;
    long total  = (long)cntM64 + (long)4 * B * cntU;
    long stride = (long)gridDim.x * 256;
    float o0 = offk[0], o1 = offk[1], o2 = offk[2];
    float sc0 = sck[0], sc1 = sck[1], sc2 = sck[2];
    int lane = threadIdx.x & 63;

    for (long vt = (long)blockIdx.x * 256 + threadIdx.x; vt < total; vt += stride) {
        if (vt < cntM64) {
            // ---------------- masked: 1 thread, all B batches ---------------
            if (vt >= cntM) continue;
            int n = idx[vt];
            float Ai[16], A[B][16];
#pragma unroll
            for (int i = 0; i < 16; ++i) Ai[i] = 0.f;
#pragma unroll
            for (int b = 0; b < B; ++b)
#pragma unroll
                for (int i = 0; i < 16; ++i) A[b][i] = 0.f;

            const float* row = lbsw + (size_t)n * JNT;
            int pre = n & 3;      // (n*55)%4 == (3n)%4 -> pre floats to 16B align

#define BLEND1(WJ, JJ)                                                         \
            {                                                                  \
                float wj_ = (WJ); int jj_ = (JJ);                              \
                const float* ti_ = sT + jj_ * 20;                              \
                _Pragma("unroll")                                              \
                for (int i = 0; i < 16; ++i) Ai[i] = fmaf(wj_, ti_[i], Ai[i]); \
                const float* tb_ = sT + JNT * 20 + jj_ * (B * 20);             \
                _Pragma("unroll")                                              \
                for (int b = 0; b < B; ++b)                                    \
                    _Pragma("unroll")                                          \
                    for (int i = 0; i < 16; ++i)                               \
                        A[b][i] = fmaf(wj_, tb_[b * 20 + i], A[b][i]);         \
            }

            int j = 0;
            for (; j < pre; ++j) BLEND1(row[j], j);
#pragma unroll 1
            for (int c = 0; c < 13; ++c, j += 4) {
                float4 w4 = *(const float4*)(row + j);
                BLEND1(w4.x, j);
                BLEND1(w4.y, j + 1);
                BLEND1(w4.z, j + 2);
                BLEND1(w4.w, j + 3);
            }
            for (; j < JNT; ++j) BLEND1(row[j], j);
#undef BLEND1

#pragma unroll
            for (int b = 0; b < B; ++b) {
                size_t p3 = ((size_t)b * N + n) * 3;
                float x = xc[p3], y = xc[p3 + 1], z = xc[p3 + 2];
                epilogue(b, n, N, x, y, z, A[b], Ai, shoff, pooff, poori,
                         out_xd, out_w);
            }
        } else {
            // ---------------- unmasked: 4-lane team per (b, point) ----------
            long ut = vt - cntM64;
            int  k  = (int)(ut & 3);
            long team = ut >> 2;
            int b = 0; long uu = team;
            while (uu >= cntU) { uu -= cntU; ++b; }
            int n = idx[N - 1 - (int)uu];

            size_t pid = (size_t)b * N + n;
            size_t p3  = pid * 3;
            float x = xc[p3], y = xc[p3 + 1], z = xc[p3 + 2];

            float px = (x + o0) * sc0;
            float py = (y + o1) * sc1;
            float pz = (z + o2) * sc2;
            float ix = fminf(fmaxf((px + 1.f) * 0.5f * (VW - 1), 0.f), (float)(VW - 1));
            float iy = fminf(fmaxf((py + 1.f) * 0.5f * (VH - 1), 0.f), (float)(VH - 1));
            float iz = fminf(fmaxf((pz + 1.f) * 0.5f * (VD - 1), 0.f), (float)(VD - 1));
            float fx = floorf(ix), fy = floorf(iy), fz = floorf(iz);
            float wx = ix - fx,    wy = iy - fy,    wz = iz - fz;
            int x0 = (int)fx, y0 = (int)fy, z0 = (int)fz;
            int x1 = min(x0 + 1, VW - 1);
            int y1 = min(y0 + 1, VH - 1);
            int z1 = min(z0 + 1, VD - 1);
            float cwx[2] = {1.f - wx, wx};
            float cwy[2] = {1.f - wy, wy};
            float cwz[2] = {1.f - wz, wz};
            int   xs[2] = {x0, x1}, ys[2] = {y0, y1}, zs[2] = {z0, z1};

            int vox[8]; float cw[8];
#pragma unroll
            for (int c = 0; c < 8; ++c) {
                int cz = c >> 2, cy = (c >> 1) & 1, cx = c & 1;
                vox[c] = (zs[cz] * VH + ys[cy]) * VW + xs[cx];
                cw[c]  = cwz[cz] * cwy[cy] * cwx[cx];
            }

            // team gather: lane k reads float4 #k of each 64B corner line
            const __half* tbb = tab + (size_t)b * NVOX * 32;
            float4 rr[8];
#pragma unroll
            for (int c = 0; c < 8; ++c)
                rr[c] = ((const float4*)(tbb + (size_t)vox[c] * 32))[k];

            float acc[8];
#pragma unroll
            for (int i = 0; i < 8; ++i) acc[i] = 0.f;
#pragma unroll
            for (int c = 0; c < 8; ++c) acc8(cw[c], rr[c], acc);

            // lane k holds elements [8k, 8k+8) of {Mi[16], Mv[16]}.
            // Reconstruct: full Ai on every lane; A row k on lane k.
            int qb = lane & ~3;
            float Ai[16];
#pragma unroll
            for (int i = 0; i < 8; ++i) Ai[i]     = __shfl(acc[i], qb + 0);
#pragma unroll
            for (int i = 0; i < 8; ++i) Ai[8 + i] = __shfl(acc[i], qb + 1);

            int src = qb + 2 + (k >> 1);
            int klo = k & 1;
            float rowk[4];
#pragma unroll
            for (int i = 0; i < 4; ++i) {
                float lo = __shfl(acc[i],     src);
                float hi = __shfl(acc[4 + i], src);
                rowk[i] = klo ? hi : lo;
            }

            // epilogue (lane k produces xd component k (k<3) and out_w row k)
            float c0 = Ai[0]*x + Ai[1]*y + Ai[2]*z  + Ai[3];
            float c1 = Ai[4]*x + Ai[5]*y + Ai[6]*z  + Ai[7];
            float c2 = Ai[8]*x + Ai[9]*y + Ai[10]*z + Ai[11];
            size_t n3 = (size_t)n * 3;
            float sx = c0 - poori[n3 + 0] + shoff[p3 + 0] + pooff[p3 + 0];
            float sy = c1 - poori[n3 + 1] + shoff[p3 + 1] + pooff[p3 + 1];
            float sz = c2 - poori[n3 + 2] + shoff[p3 + 2] + pooff[p3 + 2];
            float dk = rowk[0]*sx + rowk[1]*sy + rowk[2]*sz + rowk[3];
            if (k < 3) out_xd[p3 + k] = dk;

            float4 r;
            r.x = rowk[0]*Ai[0] + rowk[1]*Ai[4] + rowk[2]*Ai[8]  + rowk[3]*Ai[12];
            r.y = rowk[0]*Ai[1] + rowk[1]*Ai[5] + rowk[2]*Ai[9]  + rowk[3]*Ai[13];
            r.z = rowk[0]*Ai[2] + rowk[1]*Ai[6] + rowk[2]*Ai[10] + rowk[3]*Ai[14];
            r.w = rowk[0]*Ai[3] + rowk[1]*Ai[7] + rowk[2]*Ai[11] + rowk[3]*Ai[15];
            ((float4*)(out_w + pid * 16))[k] = r;
        }
    }
}

// ---------------------------------------------------------------------------
// Fallback (ws too small or B != 4): per-thread direct gather from vol.
// ---------------------------------------------------------------------------
__global__ __launch_bounds__(256) void fb_k(
    const float* __restrict__ xc, const float* __restrict__ shoff,
    const float* __restrict__ pooff, const float* __restrict__ tfs,
    const float* __restrict__ tfs_inv, const float* __restrict__ poori,
    const float* __restrict__ lbsw, const int* __restrict__ mask,
    const float* __restrict__ vol, const float* __restrict__ offk,
    const float* __restrict__ sck, float* __restrict__ out_xd,
    float* __restrict__ out_w, int N)
{
    int n = blockIdx.x * 256 + threadIdx.x;
    int b = blockIdx.y;
    if (n >= N) return;
    size_t p3 = ((size_t)b * N + n) * 3;
    float x = xc[p3], y = xc[p3 + 1], z = xc[p3 + 2];
    float A[16], Ai[16];
#pragma unroll
    for (int i = 0; i < 16; ++i) { A[i] = 0.f; Ai[i] = 0.f; }
    const float* tb = tfs + (size_t)b * JNT * 16;

    if (mask[n] != 0) {
        const float* lp = lbsw + (size_t)n * JNT;
        for (int j = 0; j < JNT; ++j) {
            float wj = lp[j];
#pragma unroll
            for (int i = 0; i < 16; ++i) Ai[i] = fmaf(wj, tfs_inv[j*16+i], Ai[i]);
#pragma unroll
            for (int i = 0; i < 16; ++i) A[i]  = fmaf(wj, tb[j*16+i],      A[i]);
        }
    } else {
        float px = (x + offk[0]) * sck[0];
        float py = (y + offk[1]) * sck[1];
        float pz = (z + offk[2]) * sck[2];
        float ix = fminf(fmaxf((px + 1.f) * 0.5f * (VW - 1), 0.f), (float)(VW - 1));
        float iy = fminf(fmaxf((py + 1.f) * 0.5f * (VH - 1), 0.f), (float)(VH - 1));
        float iz = fminf(fmaxf((pz + 1.f) * 0.5f * (VD - 1), 0.f), (float)(VD - 1));
        float fx = floorf(ix), fy = floorf(iy), fz = floorf(iz);
        float wx = ix - fx, wy = iy - fy, wz = iz - fz;
        int x0 = (int)fx, y0 = (int)fy, z0 = (int)fz;
        int x1 = min(x0 + 1, VW - 1);
        int y1 = min(y0 + 1, VH - 1);
        int z1 = min(z0 + 1, VD - 1);
        float w00 = (1.f - wz) * (1.f - wy), w01 = (1.f - wz) * wy;
        float w10 = wz * (1.f - wy),         w11 = wz * wy;
        int o00 = (z0 * VH + y0) * VW, o01 = (z0 * VH + y1) * VW;
        int o10 = (z1 * VH + y0) * VW, o11 = (z1 * VH + y1) * VW;
        for (int j = 0; j < JNT; ++j) {
            const float* vp = vol + (size_t)j * NVOX;
            float v000 = vp[o00 + x0], v001 = vp[o00 + x1];
            float v010 = vp[o01 + x0], v011 = vp[o01 + x1];
            float v100 = vp[o10 + x0], v101 = vp[o10 + x1];
            float v110 = vp[o11 + x0], v111 = vp[o11 + x1];
            float c0 = w00 * v000 + w01 * v010 + w10 * v100 + w11 * v110;
            float c1 = w00 * v001 + w01 * v011 + w10 * v101 + w11 * v111;
            float wj = c0 + wx * (c1 - c0);
#pragma unroll
            for (int i = 0; i < 16; ++i) Ai[i] = fmaf(wj, tfs_inv[j*16+i], Ai[i]);
#pragma unroll
            for (int i = 0; i < 16; ++i) A[i]  = fmaf(wj, tb[j*16+i],      A[i]);
        }
    }
    epilogue(b, n, N, x, y, z, A, Ai, shoff, pooff, poori, out_xd, out_w);
}

extern "C" void kernel_launch(void* const* d_in, const int* in_sizes, int n_in,
                              void* d_out, int out_size, void* d_ws, size_t ws_size,
                              hipStream_t stream)
{
    const float* xc    = (const float*)d_in[0];
    const float* shoff = (const float*)d_in[1];
    const float* pooff = (const float*)d_in[2];
    const float* tfs   = (const float*)d_in[3];
    const float* tfsi  = (const float*)d_in[4];
    const float* poori = (const float*)d_in[5];
    const float* lbsw  = (const float*)d_in[6];
    const int*   mask  = (const int*)d_in[7];
    const float* vol   = (const float*)d_in[8];
    const float* offk  = (const float*)d_in[9];
    const float* sck   = (const float*)d_in[10];

    int N = in_sizes[5] / 3;          // poseoff_ori [1,N,3]
    int B = in_sizes[0] / (3 * N);    // xc [B,N,3]
    float* out_xd = (float*)d_out;
    float* out_w  = (float*)d_out + (size_t)B * N * 3;

    size_t tab_bytes = (size_t)B * NVOX * 32 * sizeof(__half);
    size_t need = tab_bytes + (size_t)N * 4 + 16;
    __half* tab = (__half*)d_ws;
    int* idx = (int*)((char*)d_ws + tab_bytes);
    int* ctr = idx + N;

    if (B == 4 && ws_size >= need) {
        hipMemsetAsync(ctr, 0, 8, stream);
        build_tab_k<<<dim3((NVOX + 255) / 256), dim3(256), 0, stream>>>(
            vol, tfs, tfsi, tab, B);
        partition_k<<<dim3((N + 255) / 256), dim3(256), 0, stream>>>(
            mask, idx, ctr, N);
        main_k<4><<<dim3(4096), dim3(256), 0, stream>>>(
            xc, shoff, pooff, tfs, tfsi, poori, lbsw, tab, idx, ctr,
            offk, sck, out_xd, out_w, N);
    } else {
        fb_k<<<dim3((N + 255) / 256, B), dim3(256), 0, stream>>>(
            xc, shoff, pooff, tfs, tfsi, poori, lbsw, mask, vol, offk, sck,
            out_xd, out_w, N);
    }
}

// Round 5
// 286.674 us; speedup vs baseline: 1.4253x; 1.2538x over previous
//
#include <hip/hip_runtime.h>
#include <hip/hip_fp16.h>

// ForwardDeformer (B=4, N=250000, J=55, vol [55,16,64,64]).
// R1: pre-blend voxel grid with matrices (linearity) -> per-voxel 4x4 mats.
// R4 post-mortem: global compaction caused (a) 80-float masked accumulators ->
// spill (VGPR=64, FETCH +80MB), (b) scattered 64B out_w writes -> partial-line
// RMW (WRITE 211MB vs 76 ideal).
// R5: natural order. Team = point, lane k = batch k. Outputs fully coalesced.
// Masked: lane k owns A_k[16] + Ai row k (20 accums), coop w load + quad shfl.
// Unmasked: R4 team-gather (1 line/corner) looped over b, quad-shfl transpose.

#define JNT 55
#define VD  16
#define VH  64
#define VW  64
#define NVOX (VD * VH * VW)   // 65536

// ---------------------------------------------------------------------------
// Pre-pass: tab[(b*NVOX+v)] = 64B entry { half Mi[16], half Mv_b[16] }.
// grid.y = b, each thread writes one full 64B entry (full-line writes).
// ---------------------------------------------------------------------------
__global__ __launch_bounds__(256, 2) void build_tab_k(
    const float* __restrict__ vol, const float* __restrict__ tfs,
    const float* __restrict__ tfs_inv, __half* __restrict__ tab)
{
    int v = blockIdx.x * 256 + threadIdx.x;
    int b = blockIdx.y;
    if (v >= NVOX) return;
    float w[JNT];
#pragma unroll
    for (int j = 0; j < JNT; ++j) w[j] = vol[j * NVOX + v];

    float Mi[16], Mv[16];
#pragma unroll
    for (int i = 0; i < 16; ++i) { Mi[i] = 0.f; Mv[i] = 0.f; }
    const float* tb = tfs + (size_t)b * JNT * 16;
#pragma unroll
    for (int j = 0; j < JNT; ++j) {
        float wj = w[j];
#pragma unroll
        for (int i = 0; i < 16; ++i) Mi[i] = fmaf(wj, tfs_inv[j * 16 + i], Mi[i]);
#pragma unroll
        for (int i = 0; i < 16; ++i) Mv[i] = fmaf(wj, tb[j * 16 + i], Mv[i]);
    }
    float h[16];
#pragma unroll
    for (int i = 0; i < 8; ++i)
        h[i] = __builtin_bit_cast(float, __floats2half2_rn(Mi[2*i], Mi[2*i+1]));
#pragma unroll
    for (int i = 0; i < 8; ++i)
        h[8+i] = __builtin_bit_cast(float, __floats2half2_rn(Mv[2*i], Mv[2*i+1]));

    float4* d4 = (float4*)(tab + ((size_t)b * NVOX + v) * 32);
    d4[0] = make_float4(h[0],  h[1],  h[2],  h[3]);
    d4[1] = make_float4(h[4],  h[5],  h[6],  h[7]);
    d4[2] = make_float4(h[8],  h[9],  h[10], h[11]);
    d4[3] = make_float4(h[12], h[13], h[14], h[15]);
}

// Accumulate 8 fp16 values (one float4 of packed half2) into a[0..7].
__device__ __forceinline__ void acc8(float cw, float4 r, float* a)
{
    float rr[4] = {r.x, r.y, r.z, r.w};
#pragma unroll
    for (int kk = 0; kk < 4; ++kk) {
        __half2 h = __builtin_bit_cast(__half2, rr[kk]);
        float2 f = __half22float2(h);
        a[2*kk]     = fmaf(cw, f.x, a[2*kk]);
        a[2*kk + 1] = fmaf(cw, f.y, a[2*kk + 1]);
    }
}

__device__ __forceinline__ void epilogue(
    int b, int n, int N, float x, float y, float z,
    const float* A, const float* Ai,
    const float* __restrict__ shoff, const float* __restrict__ pooff,
    const float* __restrict__ poori,
    float* __restrict__ out_xd, float* __restrict__ out_w)
{
    size_t pid = (size_t)b * N + n;
    size_t p3  = pid * 3;
    size_t n3  = (size_t)n * 3;
    float c0 = Ai[0]*x + Ai[1]*y + Ai[2]*z  + Ai[3];
    float c1 = Ai[4]*x + Ai[5]*y + Ai[6]*z  + Ai[7];
    float c2 = Ai[8]*x + Ai[9]*y + Ai[10]*z + Ai[11];
    float sx = c0 - poori[n3 + 0] + shoff[p3 + 0] + pooff[p3 + 0];
    float sy = c1 - poori[n3 + 1] + shoff[p3 + 1] + pooff[p3 + 1];
    float sz = c2 - poori[n3 + 2] + shoff[p3 + 2] + pooff[p3 + 2];
    out_xd[p3 + 0] = A[0]*sx + A[1]*sy + A[2]*sz  + A[3];
    out_xd[p3 + 1] = A[4]*sx + A[5]*sy + A[6]*sz  + A[7];
    out_xd[p3 + 2] = A[8]*sx + A[9]*sy + A[10]*sz + A[11];

    float4* ow = (float4*)(out_w + pid * 16);
#pragma unroll
    for (int i = 0; i < 4; ++i) {
        float a0 = A[i*4+0], a1 = A[i*4+1], a2 = A[i*4+2], a3 = A[i*4+3];
        float4 r;
        r.x = a0*Ai[0] + a1*Ai[4] + a2*Ai[8]  + a3*Ai[12];
        r.y = a0*Ai[1] + a1*Ai[5] + a2*Ai[9]  + a3*Ai[13];
        r.z = a0*Ai[2] + a1*Ai[6] + a2*Ai[10] + a3*Ai[14];
        r.w = a0*Ai[3] + a1*Ai[7] + a2*Ai[11] + a3*Ai[15];
        ow[i] = r;
    }
}

// ---------------------------------------------------------------------------
// Main kernel: 256 threads = 64 teams of 4; team t -> point blockIdx.x*64+t;
// lane k of team -> batch k.
// ---------------------------------------------------------------------------
template <int B>
__global__ __launch_bounds__(256, 4) void main_k(
    const float* __restrict__ xc,
    const float* __restrict__ shoff,
    const float* __restrict__ pooff,
    const float* __restrict__ tfs,        // [B, J, 16]
    const float* __restrict__ tfs_inv,    // [J, 16]
    const float* __restrict__ poori,      // [N, 3]
    const float* __restrict__ lbsw,       // [N, J]
    const int*   __restrict__ mask,       // [N]
    const __half* __restrict__ tab,       // [B, NVOX, 32 halves]
    const float* __restrict__ offk,
    const float* __restrict__ sck,
    float* __restrict__ out_xd,
    float* __restrict__ out_w,
    int N)
{
    __shared__ float sTi[JNT * 16];       // [j][16]
    __shared__ float sT[JNT * B * 16];    // [j][b][16]
    for (int t = threadIdx.x; t < JNT * 16; t += 256) sTi[t] = tfs_inv[t];
    for (int t = threadIdx.x; t < JNT * B * 16; t += 256) {
        int j = t >> 6, r = t & 63, b = r >> 4, i = r & 15;
        sT[t] = tfs[((size_t)b * JNT + j) * 16 + i];
    }
    __syncthreads();

    int tx = threadIdx.x;
    int team = tx >> 2, k = tx & 3;
    int lane = tx & 63, qb = lane & ~3;
    int n = blockIdx.x * 64 + team;
    if (n >= N) return;

    size_t p3 = ((size_t)k * N + n) * 3;
    float x = xc[p3], y = xc[p3 + 1], z = xc[p3 + 2];
    float o0 = offk[0], o1 = offk[1], o2 = offk[2];
    float s0 = sck[0],  s1 = sck[1],  s2 = sck[2];

    float Af[16], Aif[16];
    bool m = (mask[n] != 0);

    if (m) {
        // -------- masked: lane k owns A_k[16] + Ai row k; coop w load -------
        float wl[14];
        const float* row = lbsw + (size_t)n * JNT;
#pragma unroll
        for (int i = 0; i < 14; ++i) {
            int j = 4 * i + k;
            wl[i] = (j < JNT) ? row[j] : 0.f;
        }
        float AiR[4] = {0.f, 0.f, 0.f, 0.f};
#pragma unroll
        for (int i = 0; i < 16; ++i) Af[i] = 0.f;

#pragma unroll
        for (int i = 0; i < 14; ++i) {
#pragma unroll
            for (int k2 = 0; k2 < 4; ++k2) {
                int j = 4 * i + k2;
                if (j >= JNT) continue;
                float wj = __shfl(wl[i], qb + k2);
                float4 ti = *(const float4*)(sTi + j * 16 + 4 * k);
                AiR[0] = fmaf(wj, ti.x, AiR[0]);
                AiR[1] = fmaf(wj, ti.y, AiR[1]);
                AiR[2] = fmaf(wj, ti.z, AiR[2]);
                AiR[3] = fmaf(wj, ti.w, AiR[3]);
                const float* tb = sT + (j * B + k) * 16;
#pragma unroll
                for (int q = 0; q < 4; ++q) {
                    float4 r = *(const float4*)(tb + 4 * q);
                    Af[4*q+0] = fmaf(wj, r.x, Af[4*q+0]);
                    Af[4*q+1] = fmaf(wj, r.y, Af[4*q+1]);
                    Af[4*q+2] = fmaf(wj, r.z, Af[4*q+2]);
                    Af[4*q+3] = fmaf(wj, r.w, Af[4*q+3]);
                }
            }
        }
        // reconstruct full Ai from row-split
#pragma unroll
        for (int r = 0; r < 4; ++r)
#pragma unroll
            for (int i = 0; i < 4; ++i)
                Aif[r * 4 + i] = __shfl(AiR[i], qb + r);
    } else {
        // -------- unmasked: team gather per b, quad-shfl transpose ----------
#pragma unroll
        for (int b = 0; b < B; ++b) {
            float xb = __shfl(x, qb + b);
            float yb = __shfl(y, qb + b);
            float zb = __shfl(z, qb + b);
            float px = (xb + o0) * s0;
            float py = (yb + o1) * s1;
            float pz = (zb + o2) * s2;
            float ix = fminf(fmaxf((px + 1.f) * 0.5f * (VW - 1), 0.f), (float)(VW - 1));
            float iy = fminf(fmaxf((py + 1.f) * 0.5f * (VH - 1), 0.f), (float)(VH - 1));
            float iz = fminf(fmaxf((pz + 1.f) * 0.5f * (VD - 1), 0.f), (float)(VD - 1));
            float fx = floorf(ix), fy = floorf(iy), fz = floorf(iz);
            float wx = ix - fx,    wy = iy - fy,    wz = iz - fz;
            int x0 = (int)fx, y0 = (int)fy, z0 = (int)fz;
            int x1 = min(x0 + 1, VW - 1);
            int y1 = min(y0 + 1, VH - 1);
            int z1 = min(z0 + 1, VD - 1);
            float cwx[2] = {1.f - wx, wx};
            float cwy[2] = {1.f - wy, wy};
            float cwz[2] = {1.f - wz, wz};
            int   xs[2] = {x0, x1}, ys[2] = {y0, y1}, zs[2] = {z0, z1};

            float acc[8];
#pragma unroll
            for (int i = 0; i < 8; ++i) acc[i] = 0.f;
            const __half* tbb = tab + (size_t)b * NVOX * 32;
#pragma unroll
            for (int c = 0; c < 8; ++c) {
                int cz = c >> 2, cy = (c >> 1) & 1, cx = c & 1;
                int vox = (zs[cz] * VH + ys[cy]) * VW + xs[cx];
                float cw = cwz[cz] * cwy[cy] * cwx[cx];
                float4 r4 = ((const float4*)(tbb + (size_t)vox * 32))[k];
                acc8(cw, r4, acc);
            }
            // scatter quarters to lane b: V[8*j2+i] from lane j2's acc[i]
#pragma unroll
            for (int i = 0; i < 8; ++i) {
#pragma unroll
                for (int j2 = 0; j2 < 4; ++j2) {
                    float v = __shfl(acc[i], qb + j2);
                    int dst = 8 * j2 + i;
                    if (k == b) {
                        if (dst < 16) Aif[dst] = v;
                        else          Af[dst - 16] = v;
                    }
                }
            }
        }
    }

    epilogue(k, n, N, x, y, z, Af, Aif, shoff, pooff, poori, out_xd, out_w);
}

// ---------------------------------------------------------------------------
// Fallback (ws too small or B != 4): per-thread direct gather from vol.
// ---------------------------------------------------------------------------
__global__ __launch_bounds__(256) void fb_k(
    const float* __restrict__ xc, const float* __restrict__ shoff,
    const float* __restrict__ pooff, const float* __restrict__ tfs,
    const float* __restrict__ tfs_inv, const float* __restrict__ poori,
    const float* __restrict__ lbsw, const int* __restrict__ mask,
    const float* __restrict__ vol, const float* __restrict__ offk,
    const float* __restrict__ sck, float* __restrict__ out_xd,
    float* __restrict__ out_w, int N)
{
    int n = blockIdx.x * 256 + threadIdx.x;
    int b = blockIdx.y;
    if (n >= N) return;
    size_t p3 = ((size_t)b * N + n) * 3;
    float x = xc[p3], y = xc[p3 + 1], z = xc[p3 + 2];
    float A[16], Ai[16];
#pragma unroll
    for (int i = 0; i < 16; ++i) { A[i] = 0.f; Ai[i] = 0.f; }
    const float* tb = tfs + (size_t)b * JNT * 16;

    if (mask[n] != 0) {
        const float* lp = lbsw + (size_t)n * JNT;
        for (int j = 0; j < JNT; ++j) {
            float wj = lp[j];
#pragma unroll
            for (int i = 0; i < 16; ++i) Ai[i] = fmaf(wj, tfs_inv[j*16+i], Ai[i]);
#pragma unroll
            for (int i = 0; i < 16; ++i) A[i]  = fmaf(wj, tb[j*16+i],      A[i]);
        }
    } else {
        float px = (x + offk[0]) * sck[0];
        float py = (y + offk[1]) * sck[1];
        float pz = (z + offk[2]) * sck[2];
        float ix = fminf(fmaxf((px + 1.f) * 0.5f * (VW - 1), 0.f), (float)(VW - 1));
        float iy = fminf(fmaxf((py + 1.f) * 0.5f * (VH - 1), 0.f), (float)(VH - 1));
        float iz = fminf(fmaxf((pz + 1.f) * 0.5f * (VD - 1), 0.f), (float)(VD - 1));
        float fx = floorf(ix), fy = floorf(iy), fz = floorf(iz);
        float wx = ix - fx, wy = iy - fy, wz = iz - fz;
        int x0 = (int)fx, y0 = (int)fy, z0 = (int)fz;
        int x1 = min(x0 + 1, VW - 1);
        int y1 = min(y0 + 1, VH - 1);
        int z1 = min(z0 + 1, VD - 1);
        float w00 = (1.f - wz) * (1.f - wy), w01 = (1.f - wz) * wy;
        float w10 = wz * (1.f - wy),         w11 = wz * wy;
        int o00 = (z0 * VH + y0) * VW, o01 = (z0 * VH + y1) * VW;
        int o10 = (z1 * VH + y0) * VW, o11 = (z1 * VH + y1) * VW;
        for (int j = 0; j < JNT; ++j) {
            const float* vp = vol + (size_t)j * NVOX;
            float v000 = vp[o00 + x0], v001 = vp[o00 + x1];
            float v010 = vp[o01 + x0], v011 = vp[o01 + x1];
            float v100 = vp[o10 + x0], v101 = vp[o10 + x1];
            float v110 = vp[o11 + x0], v111 = vp[o11 + x1];
            float c0 = w00 * v000 + w01 * v010 + w10 * v100 + w11 * v110;
            float c1 = w00 * v001 + w01 * v011 + w10 * v101 + w11 * v111;
            float wj = c0 + wx * (c1 - c0);
#pragma unroll
            for (int i = 0; i < 16; ++i) Ai[i] = fmaf(wj, tfs_inv[j*16+i], Ai[i]);
#pragma unroll
            for (int i = 0; i < 16; ++i) A[i]  = fmaf(wj, tb[j*16+i],      A[i]);
        }
    }
    epilogue(b, n, N, x, y, z, A, Ai, shoff, pooff, poori, out_xd, out_w);
}

extern "C" void kernel_launch(void* const* d_in, const int* in_sizes, int n_in,
                              void* d_out, int out_size, void* d_ws, size_t ws_size,
                              hipStream_t stream)
{
    const float* xc    = (const float*)d_in[0];
    const float* shoff = (const float*)d_in[1];
    const float* pooff = (const float*)d_in[2];
    const float* tfs   = (const float*)d_in[3];
    const float* tfsi  = (const float*)d_in[4];
    const float* poori = (const float*)d_in[5];
    const float* lbsw  = (const float*)d_in[6];
    const int*   mask  = (const int*)d_in[7];
    const float* vol   = (const float*)d_in[8];
    const float* offk  = (const float*)d_in[9];
    const float* sck   = (const float*)d_in[10];

    int N = in_sizes[5] / 3;          // poseoff_ori [1,N,3]
    int B = in_sizes[0] / (3 * N);    // xc [B,N,3]
    float* out_xd = (float*)d_out;
    float* out_w  = (float*)d_out + (size_t)B * N * 3;

    size_t tab_bytes = (size_t)B * NVOX * 32 * sizeof(__half);  // 16.78 MB
    __half* tab = (__half*)d_ws;

    if (B == 4 && ws_size >= tab_bytes) {
        build_tab_k<<<dim3((NVOX + 255) / 256, 4), dim3(256), 0, stream>>>(
            vol, tfs, tfsi, tab);
        main_k<4><<<dim3((N + 63) / 64), dim3(256), 0, stream>>>(
            xc, shoff, pooff, tfs, tfsi, poori, lbsw, mask, tab,
            offk, sck, out_xd, out_w, N);
    } else {
        fb_k<<<dim3((N + 255) / 256, B), dim3(256), 0, stream>>>(
            xc, shoff, pooff, tfs, tfsi, poori, lbsw, mask, vol, offk, sck,
            out_xd, out_w, N);
    }
}